// Round 1
// baseline (1732.493 us; speedup 1.0000x reference)
//
#include <hip/hip_runtime.h>
#include <math.h>

#define NH   12
#define HD   64
#define HDIM 768
#define SEQ  257
#define MIDP 128
#define BTOT 2048

// ---------------- K0: analytic LayerNorm stats for pe + pe[mid] vector ----------------
// pe_lin[s,j] = pos_s * pe_w[j] + pe_b[j];  LN over j is closed-form from 5 moments.
__global__ __launch_bounds__(256) void k0_pestats(
    const float* __restrict__ pe_w, const float* __restrict__ pe_b,
    const float* __restrict__ ln_g, const float* __restrict__ ln_b,
    float* __restrict__ stats /*[SEQ][2] mu,rstd*/, float* __restrict__ pemid /*[HDIM]*/) {
  __shared__ float red[5][256];
  const int t = threadIdx.x;
  float sw=0.f, sb=0.f, sww=0.f, swb=0.f, sbb=0.f;
  for (int j=t; j<HDIM; j+=256) {
    float w=pe_w[j], b=pe_b[j];
    sw+=w; sb+=b; sww+=w*w; swb+=w*b; sbb+=b*b;
  }
  red[0][t]=sw; red[1][t]=sb; red[2][t]=sww; red[3][t]=swb; red[4][t]=sbb;
  __syncthreads();
  for (int off=128; off>0; off>>=1) {
    if (t<off) {
      red[0][t]+=red[0][t+off]; red[1][t]+=red[1][t+off]; red[2][t]+=red[2][t+off];
      red[3][t]+=red[3][t+off]; red[4][t]+=red[4][t+off];
    }
    __syncthreads();
  }
  const float inv = 1.0f/(float)HDIM;
  const float mw=red[0][0]*inv, mc=red[1][0]*inv;
  const float Vw =red[2][0]*inv - mw*mw;
  const float Cwc=red[3][0]*inv - mw*mc;
  const float Vc =red[4][0]*inv - mc*mc;
  for (int s=t; s<SEQ; s+=256) {
    float pos = (float)(s - MIDP) / ((float)MIDP + 1e-6f);
    float mu  = pos*mw + mc;
    float var = pos*pos*Vw + 2.f*pos*Cwc + Vc;
    stats[2*s]   = mu;
    stats[2*s+1] = rsqrtf(var + 1e-5f);
  }
  const float rstd0 = rsqrtf(Vc + 1e-5f);
  for (int j=t; j<HDIM; j+=256)
    pemid[j] = (pe_b[j]-mc)*rstd0*ln_g[j] + ln_b[j];
}

// ---------------- shared tiled fp32 GEMM: C[M,N] = A[M,K] * B (+bias) ----------------
// bT=1: B[n*ldb+k]   bT=0: B[k*ldb+n]. Per-z pointer offsets for per-head batched use.
// avec (len K): added to every A row during staging (used for hs_mid + pe_mid).
// Assumes M%64==0, N%64==0, K%16==0, float4-aligned pointers/ld's.
__global__ __launch_bounds__(256) void gemm64(
    const float* __restrict__ A, long lda, long aoffz,
    const float* __restrict__ Bm, long ldb, long boffz, int bT,
    float* __restrict__ C, long ldc, long coffz,
    int K,
    const float* __restrict__ bias, long biasoffz,
    const float* __restrict__ avec) {
  __shared__ __align__(16) float As[16][68];
  __shared__ __align__(16) float Bs[16][68];
  const int tid = threadIdx.x;
  const int tx = tid & 15, ty = tid >> 4;
  const int z = blockIdx.z;
  const long n0 = (long)blockIdx.y * 64;
  A  += (long)blockIdx.x*64*lda + (long)z*aoffz;
  Bm += (long)z*boffz;
  C  += (long)blockIdx.x*64*ldc + n0 + (long)z*coffz;
  float acc[4][4] = {};
  const int lm = tid & 63;   // staged row (A) / col (B)
  const int lk = tid >> 6;   // 0..3 -> k sub-chunk

  for (int k0 = 0; k0 < K; k0 += 16) {
    float4 a = *(const float4*)&A[(long)lm*lda + k0 + lk*4];
    if (avec) {
      float4 av = *(const float4*)&avec[k0 + lk*4];
      a.x += av.x; a.y += av.y; a.z += av.z; a.w += av.w;
    }
    As[lk*4+0][lm]=a.x; As[lk*4+1][lm]=a.y; As[lk*4+2][lm]=a.z; As[lk*4+3][lm]=a.w;
    if (bT) {
      float4 b = *(const float4*)&Bm[(n0+lm)*ldb + k0 + lk*4];
      Bs[lk*4+0][lm]=b.x; Bs[lk*4+1][lm]=b.y; Bs[lk*4+2][lm]=b.z; Bs[lk*4+3][lm]=b.w;
    } else {
      #pragma unroll
      for (int i=0;i<4;i++)
        Bs[lk*4+i][lm] = Bm[(long)(k0+lk*4+i)*ldb + n0 + lm];
    }
    __syncthreads();
    #pragma unroll
    for (int k=0;k<16;k++) {
      float4 a4 = *(const float4*)&As[k][ty*4];
      float4 b4 = *(const float4*)&Bs[k][tx*4];
      float aa[4] = {a4.x,a4.y,a4.z,a4.w};
      float bb[4] = {b4.x,b4.y,b4.z,b4.w};
      #pragma unroll
      for (int i=0;i<4;i++)
        #pragma unroll
        for (int j=0;j<4;j++)
          acc[i][j] = fmaf(aa[i], bb[j], acc[i][j]);
    }
    __syncthreads();
  }
  float4 bs = make_float4(0.f,0.f,0.f,0.f);
  if (bias) bs = *(const float4*)&bias[(long)z*biasoffz + n0 + tx*4];
  #pragma unroll
  for (int i=0;i<4;i++) {
    float4 o;
    o.x = acc[i][0]+bs.x; o.y = acc[i][1]+bs.y; o.z = acc[i][2]+bs.z; o.w = acc[i][3]+bs.w;
    *(float4*)&C[(long)(ty*4+i)*ldc + tx*4] = o;
  }
}

// ---------------- kc: c[b,h] = q[b,h,:] . bk[h,:] ----------------
__global__ __launch_bounds__(256) void kc(const float* __restrict__ q,
                                          const float* __restrict__ bk,
                                          float* __restrict__ c, int nb) {
  int i = blockIdx.x*256 + threadIdx.x;
  if (i >= nb*NH) return;
  int b = i / NH, h = i % NH;
  const float* qp = q + (long)b*HDIM + h*HD;
  const float* bp = bk + h*HD;
  float s = 0.f;
  #pragma unroll 8
  for (int d=0; d<HD; d++) s = fmaf(qp[d], bp[d], s);
  c[i] = s;
}

// ---------------- K3: fused scores + online softmax + weighted-mean scan ----------------
// One block per batch. Thread t owns columns j = t, t+256, t+512.
// score[h,s] = 0.125*(u[h,:].x[s,:] + c_h) + pos_bias[h,s];  m[h,:] = sum_s p * x[s,:]
__global__ __launch_bounds__(256) void k3_scan(
    const float* __restrict__ hs, int b0,
    const float* __restrict__ u, const float* __restrict__ cbuf,
    const float* __restrict__ stats, const float* __restrict__ pos_bias,
    const float* __restrict__ pe_w, const float* __restrict__ pe_b,
    const float* __restrict__ ln_g, const float* __restrict__ ln_b,
    float* __restrict__ mout) {
  const int t = threadIdx.x;
  const int lane = t & 63;
  const int b = b0 + blockIdx.x;

  __shared__ float pb_lds[NH][SEQ+3];
  __shared__ float st_lds[2*SEQ+2];
  __shared__ float part[16][NH];
  __shared__ __align__(16) float w_lds[16];
  __shared__ __align__(16) float r_lds[16];
  __shared__ __align__(16) float sum_lds[16];

  for (int i=t; i<NH*SEQ; i+=256) pb_lds[i/SEQ][i%SEQ] = pos_bias[i];
  for (int i=t; i<2*SEQ; i+=256)  st_lds[i] = stats[i];

  float e3[3], g3[3], r3[3], lb3[3];
  #pragma unroll
  for (int k=0;k<3;k++) {
    int j = t + 256*k;
    float w=pe_w[j], pb=pe_b[j], g=ln_g[j];
    e3[k]=w*g; g3[k]=g; r3[k]=pb*g; lb3[k]=ln_b[j];
  }
  float ureg[NH][3], mreg[NH][3];
  #pragma unroll
  for (int h=0;h<NH;h++)
    #pragma unroll
    for (int k=0;k<3;k++) {
      ureg[h][k] = u[(long)blockIdx.x*(NH*HDIM) + h*HDIM + t + 256*k];
      mreg[h][k] = 0.f;
    }
  float runmax = -INFINITY, runsum = 0.f;                 // live in t<12 only
  const float c_h = (t < NH) ? cbuf[blockIdx.x*NH + t] : 0.f;
  __syncthreads();

  const float* hrow = hs + (long)b*SEQ*HDIM;
  const float inv_mid = 1.0f / ((float)MIDP + 1e-6f);
  for (int s = 0; s < SEQ; s++) {
    const float mu = st_lds[2*s], rstd = st_lds[2*s+1];
    const float pos = (float)(s - MIDP) * inv_mid;
    float x3[3], p[NH];
    #pragma unroll
    for (int k=0;k<3;k++) {
      float hv = hrow[s*HDIM + t + 256*k];
      float a = fmaf(pos, e3[k], r3[k]);
      a = fmaf(-mu, g3[k], a);
      x3[k] = fmaf(rstd, a, lb3[k]) + hv;
    }
    #pragma unroll
    for (int h=0;h<NH;h++)
      p[h] = fmaf(ureg[h][0], x3[0], fmaf(ureg[h][1], x3[1], ureg[h][2]*x3[2]));
    // butterfly within 16-lane groups (masks 1..8)
    #pragma unroll
    for (int h=0;h<NH;h++) {
      p[h] += __shfl_xor(p[h], 1);
      p[h] += __shfl_xor(p[h], 2);
      p[h] += __shfl_xor(p[h], 4);
      p[h] += __shfl_xor(p[h], 8);
    }
    if ((lane & 15) == 0) {
      const int r = t >> 4;          // 0..15
      #pragma unroll
      for (int h=0;h<NH;h++) part[r][h] = p[h];
    }
    __syncthreads();
    if (t < NH) {
      float sacc = 0.f;
      #pragma unroll
      for (int r=0;r<16;r++) sacc += part[r][t];
      float score = fmaf(0.125f, sacc + c_h, pb_lds[t][s]);
      float nm = fmaxf(runmax, score);
      float resc = __expf(runmax - nm);     // 1.0 when max unchanged
      float w = __expf(score - nm);
      runsum = fmaf(runsum, resc, w);
      runmax = nm;
      w_lds[t] = w; r_lds[t] = resc;
    }
    __syncthreads();
    const float4 wa = ((const float4*)w_lds)[0], wb = ((const float4*)w_lds)[1], wc = ((const float4*)w_lds)[2];
    const float4 ra = ((const float4*)r_lds)[0], rb = ((const float4*)r_lds)[1], rc = ((const float4*)r_lds)[2];
    const float wv12[NH] = {wa.x,wa.y,wa.z,wa.w, wb.x,wb.y,wb.z,wb.w, wc.x,wc.y,wc.z,wc.w};
    const float rv12[NH] = {ra.x,ra.y,ra.z,ra.w, rb.x,rb.y,rb.z,rb.w, rc.x,rc.y,rc.z,rc.w};
    #pragma unroll
    for (int h=0;h<NH;h++)
      #pragma unroll
      for (int k=0;k<3;k++)
        mreg[h][k] = fmaf(wv12[h], x3[k], mreg[h][k]*rv12[h]);
  }
  if (t < NH) sum_lds[t] = 1.0f / runsum;
  __syncthreads();
  const float4 sa = ((const float4*)sum_lds)[0], sb = ((const float4*)sum_lds)[1], sc = ((const float4*)sum_lds)[2];
  const float sv[NH] = {sa.x,sa.y,sa.z,sa.w, sb.x,sb.y,sb.z,sb.w, sc.x,sc.y,sc.z,sc.w};
  #pragma unroll
  for (int h=0;h<NH;h++)
    #pragma unroll
    for (int k=0;k<3;k++)
      mout[(long)blockIdx.x*(NH*HDIM) + h*HDIM + t + 256*k] = mreg[h][k]*sv[h];
}

extern "C" void kernel_launch(void* const* d_in, const int* in_sizes, int n_in,
                              void* d_out, int out_size, void* d_ws, size_t ws_size,
                              hipStream_t stream) {
  (void)in_sizes; (void)n_in; (void)out_size;
  const float* hs   = (const float*)d_in[0];
  const float* Wq   = (const float*)d_in[1];
  const float* bq   = (const float*)d_in[2];
  const float* Wk   = (const float*)d_in[3];
  const float* bk   = (const float*)d_in[4];
  const float* Wv   = (const float*)d_in[5];
  const float* bv   = (const float*)d_in[6];
  const float* Wo   = (const float*)d_in[7];
  const float* bo   = (const float*)d_in[8];
  const float* pe_w = (const float*)d_in[9];
  const float* pe_b = (const float*)d_in[10];
  const float* ln_g = (const float*)d_in[11];
  const float* ln_b = (const float*)d_in[12];
  const float* pos_bias = (const float*)d_in[13];
  float* out = (float*)d_out;

  float* wsf = (float*)d_ws;
  float* stats = wsf;                 // 516 floats (514 used)
  float* pemid = wsf + 516;           // 768
  float* base  = wsf + 516 + 768;     // 16B-aligned (1284*4 = 5136)

  const long perB = (long)HDIM + NH + 2L*NH*HDIM + HDIM;   // q + c + u + m + ctx
  long availF = (long)(ws_size/4) - 1284;
  long chunkB = (availF > 0) ? (availF / perB) : 0;
  if (chunkB > BTOT) chunkB = BTOT;
  chunkB &= ~63L;
  if (chunkB < 64) chunkB = 64;       // minimum viable chunk (~5.2 MB ws)

  float* qb   = base;
  float* cb   = qb  + chunkB*HDIM;
  float* ub   = cb  + chunkB*NH;
  float* mb   = ub  + chunkB*(long)NH*HDIM;
  float* ctxb = mb  + chunkB*(long)NH*HDIM;

  k0_pestats<<<dim3(1), dim3(256), 0, stream>>>(pe_w, pe_b, ln_g, ln_b, stats, pemid);

  for (long b0 = 0; b0 < BTOT; b0 += chunkB) {
    long cbN = (BTOT - b0 < chunkB) ? (BTOT - b0) : chunkB;
    int mt = (int)(cbN/64);
    // K1: q = (hs[:,mid,:] + pe_mid) @ Wq^T + bq
    gemm64<<<dim3(mt,12,1), dim3(256), 0, stream>>>(
        hs + b0*(long)SEQ*HDIM + (long)MIDP*HDIM, (long)SEQ*HDIM, 0L,
        Wq, (long)HDIM, 0L, 1,
        qb, (long)HDIM, 0L,
        HDIM, bq, 0L, pemid);
    // c[b,h] = q . bk
    int nthr = (int)(cbN*NH);
    kc<<<dim3((nthr+255)/256), dim3(256), 0, stream>>>(qb, bk, cb, (int)cbN);
    // K2: u[b,h,:] = q[b,h,:] @ Wk_h   (per-head, N-layout B)
    gemm64<<<dim3(mt,12,12), dim3(256), 0, stream>>>(
        qb, (long)HDIM, (long)HD,
        Wk, (long)HDIM, (long)HD*HDIM, 0,
        ub, (long)NH*HDIM, (long)HDIM,
        HD, (const float*)nullptr, 0L, (const float*)nullptr);
    // K3: fused scan -> m (normalized weighted mean of x per head)
    k3_scan<<<dim3((int)cbN), dim3(256), 0, stream>>>(
        hs, (int)b0, ub, cb, stats, pos_bias, pe_w, pe_b, ln_g, ln_b, mb);
    // K4: ctx[b,h*64+d] = Wv_h @ m[b,h,:] + bv  (per-head, B^T)
    gemm64<<<dim3(mt,1,12), dim3(256), 0, stream>>>(
        mb, (long)NH*HDIM, (long)HDIM,
        Wv, (long)HDIM, (long)HD*HDIM, 1,
        ctxb, (long)HDIM, (long)HD,
        HDIM, bv, (long)HD, (const float*)nullptr);
    // K5: out = ctx @ Wo^T + bo
    gemm64<<<dim3(mt,12,1), dim3(256), 0, stream>>>(
        ctxb, (long)HDIM, 0L,
        Wo, (long)HDIM, 0L, 1,
        out + b0*(long)HDIM, (long)HDIM, 0L,
        HDIM, bo, 0L, (const float*)nullptr);
  }
}

// Round 2
// 1277.801 us; speedup vs baseline: 1.3558x; 1.3558x over previous
//
#include <hip/hip_runtime.h>
#include <math.h>

#define NH   12
#define HD   64
#define HDIM 768
#define SEQ  257
#define MIDP 128
#define BTOT 2048
#define CS   8
#define XPAD 772   // floats per x_lds row (768 + 4) — breaks power-of-2 bank stride

// ---------------- K0: analytic LayerNorm stats for pe + pe[mid] vector ----------------
__global__ __launch_bounds__(256) void k0_pestats(
    const float* __restrict__ pe_w, const float* __restrict__ pe_b,
    const float* __restrict__ ln_g, const float* __restrict__ ln_b,
    float* __restrict__ stats /*[SEQ][2] mu,rstd*/, float* __restrict__ pemid /*[HDIM]*/) {
  __shared__ float red[5][256];
  const int t = threadIdx.x;
  float sw=0.f, sb=0.f, sww=0.f, swb=0.f, sbb=0.f;
  for (int j=t; j<HDIM; j+=256) {
    float w=pe_w[j], b=pe_b[j];
    sw+=w; sb+=b; sww+=w*w; swb+=w*b; sbb+=b*b;
  }
  red[0][t]=sw; red[1][t]=sb; red[2][t]=sww; red[3][t]=swb; red[4][t]=sbb;
  __syncthreads();
  for (int off=128; off>0; off>>=1) {
    if (t<off) {
      red[0][t]+=red[0][t+off]; red[1][t]+=red[1][t+off]; red[2][t]+=red[2][t+off];
      red[3][t]+=red[3][t+off]; red[4][t]+=red[4][t+off];
    }
    __syncthreads();
  }
  const float inv = 1.0f/(float)HDIM;
  const float mw=red[0][0]*inv, mc=red[1][0]*inv;
  const float Vw =red[2][0]*inv - mw*mw;
  const float Cwc=red[3][0]*inv - mw*mc;
  const float Vc =red[4][0]*inv - mc*mc;
  for (int s=t; s<SEQ; s+=256) {
    float pos = (float)(s - MIDP) / ((float)MIDP + 1e-6f);
    float mu  = pos*mw + mc;
    float var = pos*pos*Vw + 2.f*pos*Cwc + Vc;
    stats[2*s]   = mu;
    stats[2*s+1] = rsqrtf(var + 1e-5f);
  }
  const float rstd0 = rsqrtf(Vc + 1e-5f);
  for (int j=t; j<HDIM; j+=256)
    pemid[j] = (pe_b[j]-mc)*rstd0*ln_g[j] + ln_b[j];
}

// ---------------- K0b: materialize pe table [SEQ][HDIM] (L3-resident, 789 KB) ----------------
__global__ __launch_bounds__(256) void k0b_petab(
    const float* __restrict__ stats,
    const float* __restrict__ pe_w, const float* __restrict__ pe_b,
    const float* __restrict__ ln_g, const float* __restrict__ ln_b,
    float* __restrict__ pe_tab) {
  const int s = blockIdx.x;
  const float mu = stats[2*s], rstd = stats[2*s+1];
  const float pos = (float)(s - MIDP) / ((float)MIDP + 1e-6f);
  for (int j = threadIdx.x; j < HDIM; j += 256) {
    float v = fmaf(pos, pe_w[j], pe_b[j]);
    pe_tab[(long)s*HDIM + j] = (v - mu)*rstd*ln_g[j] + ln_b[j];
  }
}

// ---------------- shared tiled fp32 GEMM (unchanged) ----------------
__global__ __launch_bounds__(256) void gemm64(
    const float* __restrict__ A, long lda, long aoffz,
    const float* __restrict__ Bm, long ldb, long boffz, int bT,
    float* __restrict__ C, long ldc, long coffz,
    int K,
    const float* __restrict__ bias, long biasoffz,
    const float* __restrict__ avec) {
  __shared__ __align__(16) float As[16][68];
  __shared__ __align__(16) float Bs[16][68];
  const int tid = threadIdx.x;
  const int tx = tid & 15, ty = tid >> 4;
  const int z = blockIdx.z;
  const long n0 = (long)blockIdx.y * 64;
  A  += (long)blockIdx.x*64*lda + (long)z*aoffz;
  Bm += (long)z*boffz;
  C  += (long)blockIdx.x*64*ldc + n0 + (long)z*coffz;
  float acc[4][4] = {};
  const int lm = tid & 63;
  const int lk = tid >> 6;

  for (int k0 = 0; k0 < K; k0 += 16) {
    float4 a = *(const float4*)&A[(long)lm*lda + k0 + lk*4];
    if (avec) {
      float4 av = *(const float4*)&avec[k0 + lk*4];
      a.x += av.x; a.y += av.y; a.z += av.z; a.w += av.w;
    }
    As[lk*4+0][lm]=a.x; As[lk*4+1][lm]=a.y; As[lk*4+2][lm]=a.z; As[lk*4+3][lm]=a.w;
    if (bT) {
      float4 b = *(const float4*)&Bm[(n0+lm)*ldb + k0 + lk*4];
      Bs[lk*4+0][lm]=b.x; Bs[lk*4+1][lm]=b.y; Bs[lk*4+2][lm]=b.z; Bs[lk*4+3][lm]=b.w;
    } else {
      #pragma unroll
      for (int i=0;i<4;i++)
        Bs[lk*4+i][lm] = Bm[(long)(k0+lk*4+i)*ldb + n0 + lm];
    }
    __syncthreads();
    #pragma unroll
    for (int k=0;k<16;k++) {
      float4 a4 = *(const float4*)&As[k][ty*4];
      float4 b4 = *(const float4*)&Bs[k][tx*4];
      float aa[4] = {a4.x,a4.y,a4.z,a4.w};
      float bb[4] = {b4.x,b4.y,b4.z,b4.w};
      #pragma unroll
      for (int i=0;i<4;i++)
        #pragma unroll
        for (int j=0;j<4;j++)
          acc[i][j] = fmaf(aa[i], bb[j], acc[i][j]);
    }
    __syncthreads();
  }
  float4 bs = make_float4(0.f,0.f,0.f,0.f);
  if (bias) bs = *(const float4*)&bias[(long)z*biasoffz + n0 + tx*4];
  #pragma unroll
  for (int i=0;i<4;i++) {
    float4 o;
    o.x = acc[i][0]+bs.x; o.y = acc[i][1]+bs.y; o.z = acc[i][2]+bs.z; o.w = acc[i][3]+bs.w;
    *(float4*)&C[(long)(ty*4+i)*ldc + tx*4] = o;
  }
}

// ---------------- kc: c[b,h] = q[b,h,:] . bk[h,:] ----------------
__global__ __launch_bounds__(256) void kc(const float* __restrict__ q,
                                          const float* __restrict__ bk,
                                          float* __restrict__ c, int nb) {
  int i = blockIdx.x*256 + threadIdx.x;
  if (i >= nb*NH) return;
  int b = i / NH, h = i % NH;
  const float* qp = q + (long)b*HDIM + h*HD;
  const float* bp = bk + h*HD;
  float s = 0.f;
  #pragma unroll 8
  for (int d=0; d<HD; d++) s = fmaf(qp[d], bp[d], s);
  c[i] = s;
}

// ---------------- K3 v2: chunked scores + exp + weighted-sum scan (no online max) ----------------
// Block per batch. Chunk of 8 s-rows staged in LDS (hs + pe_tab).
// Phase B: wave wv owns heads h0..h0+2; lane owns 12 contiguous cols (u in regs);
//          full 64-lane xor-reduce per (h,cs); w = exp(score) -> w_lds.
// Phase C: all threads accumulate m[h][k] += w[h]*x[k] (cols t, t+256, t+512).
__global__ __launch_bounds__(256, 4) void k3_scan(
    const float* __restrict__ hs, int b0,
    const float* __restrict__ u, const float* __restrict__ cbuf,
    const float* __restrict__ pe_tab, const float* __restrict__ pos_bias,
    float* __restrict__ mout) {
  const int t = threadIdx.x;
  const int lane = t & 63;
  const int wv = t >> 6;
  const int h0 = wv * 3;
  const int b = b0 + blockIdx.x;

  __shared__ __align__(16) float x_lds[CS][XPAD];
  __shared__ __align__(16) float w_lds[CS][16];
  __shared__ __align__(16) float sum_lds[16];

  // u (Wk_h^T q) register-resident: rows h0..h0+2, cols lane*12..lane*12+11
  const float* ub = u + (long)blockIdx.x * (NH*HDIM);
  float4 u4[3][3];
  #pragma unroll
  for (int i=0;i<3;i++)
    #pragma unroll
    for (int e=0;e<3;e++)
      u4[i][e] = *(const float4*)&ub[(h0+i)*HDIM + lane*12 + e*4];

  float c3[3], rs[3] = {0.f, 0.f, 0.f};
  #pragma unroll
  for (int i=0;i<3;i++) c3[i] = cbuf[blockIdx.x*NH + h0 + i];

  float m[NH][3];
  #pragma unroll
  for (int h=0;h<NH;h++) { m[h][0]=0.f; m[h][1]=0.f; m[h][2]=0.f; }

  const float* hrow = hs + (long)b * SEQ * HDIM;
  const int r  = t >> 5;          // staging row 0..7
  const int cg = (t & 31) * 6;    // float4 index within row

  for (int s0 = 0; s0 < SEQ; s0 += CS) {
    const int CN = (SEQ - s0 < CS) ? (SEQ - s0) : CS;
    // ---- stage: x = hs + pe ----
    if (r < CN) {
      const float4* hsr = (const float4*)(hrow + (long)(s0 + r) * HDIM);
      const float4* per = (const float4*)(pe_tab + (long)(s0 + r) * HDIM);
      #pragma unroll
      for (int e=0;e<6;e++) {
        float4 a = hsr[cg+e], p = per[cg+e];
        a.x+=p.x; a.y+=p.y; a.z+=p.z; a.w+=p.w;
        *(float4*)&x_lds[r][(cg+e)*4] = a;
      }
    }
    __syncthreads();
    // ---- phase B: scores -> exp -> w_lds ----
    for (int cs=0; cs<CN; ++cs) {
      float4 xa = *(const float4*)&x_lds[cs][lane*12];
      float4 xb = *(const float4*)&x_lds[cs][lane*12+4];
      float4 xc = *(const float4*)&x_lds[cs][lane*12+8];
      float p3[3];
      #pragma unroll
      for (int i=0;i<3;i++) {
        float pp =        u4[i][0].x*xa.x;
        pp = fmaf(u4[i][0].y, xa.y, pp);
        pp = fmaf(u4[i][0].z, xa.z, pp);
        pp = fmaf(u4[i][0].w, xa.w, pp);
        pp = fmaf(u4[i][1].x, xb.x, pp);
        pp = fmaf(u4[i][1].y, xb.y, pp);
        pp = fmaf(u4[i][1].z, xb.z, pp);
        pp = fmaf(u4[i][1].w, xb.w, pp);
        pp = fmaf(u4[i][2].x, xc.x, pp);
        pp = fmaf(u4[i][2].y, xc.y, pp);
        pp = fmaf(u4[i][2].z, xc.z, pp);
        pp = fmaf(u4[i][2].w, xc.w, pp);
        p3[i] = pp;
      }
      #pragma unroll
      for (int mlog=0; mlog<6; mlog++) {
        const int msk = 1 << mlog;
        p3[0] += __shfl_xor(p3[0], msk);
        p3[1] += __shfl_xor(p3[1], msk);
        p3[2] += __shfl_xor(p3[2], msk);
      }
      #pragma unroll
      for (int i=0;i<3;i++) {
        float sc = fmaf(0.125f, p3[i] + c3[i], pos_bias[(h0+i)*SEQ + s0 + cs]);
        float w  = __expf(sc);
        rs[i] += w;
        if (lane == 0) w_lds[cs][h0+i] = w;
      }
    }
    __syncthreads();
    // ---- phase C: m += w * x ----
    for (int cs=0; cs<CN; ++cs) {
      float4 wa = *(const float4*)&w_lds[cs][0];
      float4 wb = *(const float4*)&w_lds[cs][4];
      float4 wc = *(const float4*)&w_lds[cs][8];
      const float wvk[NH] = {wa.x,wa.y,wa.z,wa.w, wb.x,wb.y,wb.z,wb.w, wc.x,wc.y,wc.z,wc.w};
      float x0 = x_lds[cs][t], x1 = x_lds[cs][t+256], x2 = x_lds[cs][t+512];
      #pragma unroll
      for (int h=0;h<NH;h++) {
        m[h][0] = fmaf(wvk[h], x0, m[h][0]);
        m[h][1] = fmaf(wvk[h], x1, m[h][1]);
        m[h][2] = fmaf(wvk[h], x2, m[h][2]);
      }
    }
    __syncthreads();
  }
  if (lane == 0) { sum_lds[h0+0]=rs[0]; sum_lds[h0+1]=rs[1]; sum_lds[h0+2]=rs[2]; }
  __syncthreads();
  float* mo = mout + (long)blockIdx.x * (NH*HDIM);
  #pragma unroll
  for (int h=0;h<NH;h++) {
    float inv = 1.0f / sum_lds[h];
    mo[h*HDIM + t]       = m[h][0]*inv;
    mo[h*HDIM + t + 256] = m[h][1]*inv;
    mo[h*HDIM + t + 512] = m[h][2]*inv;
  }
}

extern "C" void kernel_launch(void* const* d_in, const int* in_sizes, int n_in,
                              void* d_out, int out_size, void* d_ws, size_t ws_size,
                              hipStream_t stream) {
  (void)in_sizes; (void)n_in; (void)out_size;
  const float* hs   = (const float*)d_in[0];
  const float* Wq   = (const float*)d_in[1];
  const float* bq   = (const float*)d_in[2];
  const float* Wk   = (const float*)d_in[3];
  const float* bk   = (const float*)d_in[4];
  const float* Wv   = (const float*)d_in[5];
  const float* bv   = (const float*)d_in[6];
  const float* Wo   = (const float*)d_in[7];
  const float* bo   = (const float*)d_in[8];
  const float* pe_w = (const float*)d_in[9];
  const float* pe_b = (const float*)d_in[10];
  const float* ln_g = (const float*)d_in[11];
  const float* ln_b = (const float*)d_in[12];
  const float* pos_bias = (const float*)d_in[13];
  float* out = (float*)d_out;

  float* wsf   = (float*)d_ws;
  float* stats = wsf;                       // 516
  float* pemid = wsf + 516;                 // 768
  float* petab = wsf + 516 + 768;           // SEQ*HDIM = 197376
  float* base  = petab + (long)SEQ*HDIM;    // chunked buffers

  const long perB = (long)HDIM + NH + 2L*NH*HDIM + HDIM;   // q + c + u + m + ctx
  long availF = (long)(ws_size/4) - (516 + 768 + (long)SEQ*HDIM);
  long chunkB = (availF > 0) ? (availF / perB) : 0;
  if (chunkB > BTOT) chunkB = BTOT;
  chunkB &= ~63L;
  if (chunkB < 64) chunkB = 64;

  float* qb   = base;
  float* cb   = qb  + chunkB*HDIM;
  float* ub   = cb  + chunkB*NH;
  float* mb   = ub  + chunkB*(long)NH*HDIM;
  float* ctxb = mb  + chunkB*(long)NH*HDIM;

  k0_pestats<<<dim3(1), dim3(256), 0, stream>>>(pe_w, pe_b, ln_g, ln_b, stats, pemid);
  k0b_petab<<<dim3(SEQ), dim3(256), 0, stream>>>(stats, pe_w, pe_b, ln_g, ln_b, petab);

  for (long b0 = 0; b0 < BTOT; b0 += chunkB) {
    long cbN = (BTOT - b0 < chunkB) ? (BTOT - b0) : chunkB;
    int mt = (int)(cbN/64);
    // K1: q = (hs[:,mid,:] + pe_mid) @ Wq^T + bq
    gemm64<<<dim3(mt,12,1), dim3(256), 0, stream>>>(
        hs + b0*(long)SEQ*HDIM + (long)MIDP*HDIM, (long)SEQ*HDIM, 0L,
        Wq, (long)HDIM, 0L, 1,
        qb, (long)HDIM, 0L,
        HDIM, bq, 0L, pemid);
    // c[b,h] = q . bk
    int nthr = (int)(cbN*NH);
    kc<<<dim3((nthr+255)/256), dim3(256), 0, stream>>>(qb, bk, cb, (int)cbN);
    // K2: u[b,h,:] = q[b,h,:] @ Wk_h
    gemm64<<<dim3(mt,12,12), dim3(256), 0, stream>>>(
        qb, (long)HDIM, (long)HD,
        Wk, (long)HDIM, (long)HD*HDIM, 0,
        ub, (long)NH*HDIM, (long)HDIM,
        HD, (const float*)nullptr, 0L, (const float*)nullptr);
    // K3: fused scan -> m
    k3_scan<<<dim3((int)cbN), dim3(256), 0, stream>>>(
        hs, (int)b0, ub, cb, petab, pos_bias, mb);
    // K4: ctx = Wv_h @ m + bv
    gemm64<<<dim3(mt,1,12), dim3(256), 0, stream>>>(
        mb, (long)NH*HDIM, (long)HDIM,
        Wv, (long)HDIM, (long)HD*HDIM, 1,
        ctxb, (long)HDIM, (long)HD,
        HDIM, bv, (long)HD, (const float*)nullptr);
    // K5: out = ctx @ Wo^T + bo
    gemm64<<<dim3(mt,12,1), dim3(256), 0, stream>>>(
        ctxb, (long)HDIM, 0L,
        Wo, (long)HDIM, 0L, 1,
        out + b0*(long)HDIM, (long)HDIM, 0L,
        HDIM, bo, 0L, (const float*)nullptr);
  }
}

// Round 3
// 831.147 us; speedup vs baseline: 2.0845x; 1.5374x over previous
//
#include <hip/hip_runtime.h>
#include <math.h>

#define NH   12
#define HD   64
#define HDIM 768
#define SEQ  257
#define MIDP 128
#define BTOT 2048

typedef __attribute__((ext_vector_type(8))) short short8;
typedef __attribute__((ext_vector_type(4))) float f32x4;

__device__ inline unsigned short f2bf(float x){
  union { float f; unsigned u; } v; v.f = x;
  unsigned r = v.u + 0x7FFFu + ((v.u >> 16) & 1u);
  return (unsigned short)(r >> 16);
}
__device__ inline float bf2f(unsigned short h){
  union { unsigned u; float f; } v; v.u = ((unsigned)h) << 16; return v.f;
}
__device__ inline uint4 pack8(float4 a, float4 b){
  uint4 r;
  r.x = (unsigned)f2bf(a.x) | ((unsigned)f2bf(a.y) << 16);
  r.y = (unsigned)f2bf(a.z) | ((unsigned)f2bf(a.w) << 16);
  r.z = (unsigned)f2bf(b.x) | ((unsigned)f2bf(b.y) << 16);
  r.w = (unsigned)f2bf(b.z) | ((unsigned)f2bf(b.w) << 16);
  return r;
}
__device__ inline float dot4(float4 a, float4 b){
  return fmaf(a.x,b.x, fmaf(a.y,b.y, fmaf(a.z,b.z, a.w*b.w)));
}

// ---------------- K0: moments + pe rank-3 decomposition tables ----------------
// pe[s,j] = alpha_s*A_j + beta_s*B_j + C_j ; alpha=pos*rstd, beta=rstd
__global__ __launch_bounds__(256) void k0_pre(
    const float* __restrict__ pe_w, const float* __restrict__ pe_b,
    const float* __restrict__ ln_g, const float* __restrict__ ln_b,
    const float* __restrict__ pos_bias,
    float* __restrict__ pemid, float* __restrict__ alpha, float* __restrict__ beta,
    float* __restrict__ Av, float* __restrict__ Bv, float* __restrict__ Cv,
    float* __restrict__ pbT) {
  __shared__ float red[5][256];
  const int t = threadIdx.x;
  float sw=0.f, sb=0.f, sww=0.f, swb=0.f, sbb=0.f;
  for (int j=t; j<HDIM; j+=256) {
    float w=pe_w[j], b=pe_b[j];
    sw+=w; sb+=b; sww+=w*w; swb+=w*b; sbb+=b*b;
  }
  red[0][t]=sw; red[1][t]=sb; red[2][t]=sww; red[3][t]=swb; red[4][t]=sbb;
  __syncthreads();
  for (int off=128; off>0; off>>=1) {
    if (t<off) {
      red[0][t]+=red[0][t+off]; red[1][t]+=red[1][t+off]; red[2][t]+=red[2][t+off];
      red[3][t]+=red[3][t+off]; red[4][t]+=red[4][t+off];
    }
    __syncthreads();
  }
  const float inv = 1.0f/(float)HDIM;
  const float mw=red[0][0]*inv, mc=red[1][0]*inv;
  const float Vw =red[2][0]*inv - mw*mw;
  const float Cwc=red[3][0]*inv - mw*mc;
  const float Vc =red[4][0]*inv - mc*mc;
  for (int s=t; s<272; s+=256) {
    if (s < SEQ) {
      float pos = (float)(s - MIDP) / ((float)MIDP + 1e-6f);
      float var = pos*pos*Vw + 2.f*pos*Cwc + Vc;
      float rstd = rsqrtf(var + 1e-5f);
      alpha[s] = pos*rstd; beta[s] = rstd;
    } else { alpha[s] = 0.f; beta[s] = 0.f; }
  }
  const float rstd0 = rsqrtf(Vc + 1e-5f);
  for (int j=t; j<HDIM; j+=256) {
    float g = ln_g[j];
    Av[j] = (pe_w[j]-mw)*g;
    Bv[j] = (pe_b[j]-mc)*g;
    Cv[j] = ln_b[j];
    pemid[j] = (pe_b[j]-mc)*rstd0*g + ln_b[j];
  }
  for (int i=t; i<272*16; i+=256) {
    int s = i>>4, h = i&15;
    pbT[i] = (s<SEQ && h<NH) ? pos_bias[h*SEQ+s] : 0.f;
  }
}

// ---------------- tiled fp32 GEMM with epilogue scale ----------------
__global__ __launch_bounds__(256) void gemm64(
    const float* __restrict__ A, long lda, long aoffz,
    const float* __restrict__ Bm, long ldb, long boffz, int bT,
    float* __restrict__ C, long ldc, long coffz,
    int K,
    const float* __restrict__ bias, long biasoffz,
    const float* __restrict__ avec, float scale) {
  __shared__ __align__(16) float As[16][68];
  __shared__ __align__(16) float Bs[16][68];
  const int tid = threadIdx.x;
  const int tx = tid & 15, ty = tid >> 4;
  const int z = blockIdx.z;
  const long n0 = (long)blockIdx.y * 64;
  A  += (long)blockIdx.x*64*lda + (long)z*aoffz;
  Bm += (long)z*boffz;
  C  += (long)blockIdx.x*64*ldc + n0 + (long)z*coffz;
  float acc[4][4] = {};
  const int lm = tid & 63;
  const int lk = tid >> 6;

  for (int k0 = 0; k0 < K; k0 += 16) {
    float4 a = *(const float4*)&A[(long)lm*lda + k0 + lk*4];
    if (avec) {
      float4 av = *(const float4*)&avec[k0 + lk*4];
      a.x += av.x; a.y += av.y; a.z += av.z; a.w += av.w;
    }
    As[lk*4+0][lm]=a.x; As[lk*4+1][lm]=a.y; As[lk*4+2][lm]=a.z; As[lk*4+3][lm]=a.w;
    if (bT) {
      float4 b = *(const float4*)&Bm[(n0+lm)*ldb + k0 + lk*4];
      Bs[lk*4+0][lm]=b.x; Bs[lk*4+1][lm]=b.y; Bs[lk*4+2][lm]=b.z; Bs[lk*4+3][lm]=b.w;
    } else {
      #pragma unroll
      for (int i=0;i<4;i++)
        Bs[lk*4+i][lm] = Bm[(long)(k0+lk*4+i)*ldb + n0 + lm];
    }
    __syncthreads();
    #pragma unroll
    for (int k=0;k<16;k++) {
      float4 a4 = *(const float4*)&As[k][ty*4];
      float4 b4 = *(const float4*)&Bs[k][tx*4];
      float aa[4] = {a4.x,a4.y,a4.z,a4.w};
      float bb[4] = {b4.x,b4.y,b4.z,b4.w};
      #pragma unroll
      for (int i=0;i<4;i++)
        #pragma unroll
        for (int j=0;j<4;j++)
          acc[i][j] = fmaf(aa[i], bb[j], acc[i][j]);
    }
    __syncthreads();
  }
  float4 bs = make_float4(0.f,0.f,0.f,0.f);
  if (bias) bs = *(const float4*)&bias[(long)z*biasoffz + n0 + tx*4];
  #pragma unroll
  for (int i=0;i<4;i++) {
    float4 o;
    o.x = (acc[i][0]+bs.x)*scale; o.y = (acc[i][1]+bs.y)*scale;
    o.z = (acc[i][2]+bs.z)*scale; o.w = (acc[i][3]+bs.w)*scale;
    *(float4*)&C[(long)(ty*4+i)*ldc + tx*4] = o;
  }
}

// ---------------- kp: per-(b,h) scalars ca=u'.A, cb=u'.B, cc=u'.C + q'.bk ----------------
__global__ __launch_bounds__(256) void kp(
    const float* __restrict__ q, const float* __restrict__ u, const float* __restrict__ bk,
    const float* __restrict__ Av, const float* __restrict__ Bv, const float* __restrict__ Cv,
    float* __restrict__ ca, float* __restrict__ cb, float* __restrict__ cc, int nb) {
  const int wid = blockIdx.x*4 + (threadIdx.x >> 6);
  const int lane = threadIdx.x & 63;
  if (wid >= nb*NH) return;
  const int b = wid / NH, h = wid % NH;
  const float* up = u + (long)b*(NH*HDIM) + h*HDIM;
  float pa=0.f, pb_=0.f, pc=0.f;
  #pragma unroll
  for (int e=0;e<3;e++) {
    int c4 = (lane + 64*e)*4;
    float4 uu = *(const float4*)&up[c4];
    pa += dot4(uu, *(const float4*)&Av[c4]);
    pb_+= dot4(uu, *(const float4*)&Bv[c4]);
    pc += dot4(uu, *(const float4*)&Cv[c4]);
  }
  if (lane < 16) {
    float4 qq = *(const float4*)&q[(long)b*HDIM + h*HD + lane*4];
    float4 bb = *(const float4*)&bk[h*HD + lane*4];
    pc += dot4(qq, bb);
  }
  #pragma unroll
  for (int mlog=0; mlog<6; mlog++) {
    int msk = 1<<mlog;
    pa += __shfl_xor(pa, msk);
    pb_+= __shfl_xor(pb_, msk);
    pc += __shfl_xor(pc, msk);
  }
  if (lane == 0) { ca[wid]=pa; cb[wid]=pb_; cc[wid]=pc; }
}

// ---------------- K3: MFMA scores + exp + VALU weighted-mean, raw-hs streaming ----------------
// Block per batch. 16-row chunks of raw hs staged as swizzled bf16.
// G1: S(16s x 16h) = x_bf16 * u'^T via mfma 16x16x32, K=768 split 4 ways over waves.
// score = S + ca*alpha_s + cb*beta_s + cc + pbT[s][h]; w = exp(score) (masked s<257).
// Phase C (VALU): m_raw[h][col] += w*x. Epilogue: m=(m_raw + sa*A + sb*B + r*C)/r.
__global__ __launch_bounds__(256) void k3_mfma(
    const float* __restrict__ hs, int b0,
    const float* __restrict__ u,
    const float* __restrict__ ca, const float* __restrict__ cb, const float* __restrict__ cc,
    const float* __restrict__ alpha, const float* __restrict__ beta,
    const float* __restrict__ Av, const float* __restrict__ Bv, const float* __restrict__ Cv,
    const float* __restrict__ pbT, float* __restrict__ mout) {
  const int t   = threadIdx.x;
  const int l   = t & 63;
  const int w   = t >> 6;
  const int l15 = l & 15;
  const int lg  = l >> 4;
  const int bb  = blockIdx.x;
  const int b   = b0 + bb;

  __shared__ unsigned short xbf[16*768];          // swizzled bf16 chunk
  __shared__ float sred[3*16*17];                 // partial C from waves 1..3
  __shared__ float wl[16*16];                     // w[s][h]
  __shared__ float al_s[272], be_s[272];
  __shared__ float hsum[3][12];

  for (int i=t; i<272; i+=256) { al_s[i]=alpha[i]; be_s[i]=beta[i]; }

  // u'-fragments (B operand), wave w covers K-cols [w*192, w*192+192)
  const float* ub = u + (long)bb*(NH*HDIM);
  short8 uf[6];
  #pragma unroll
  for (int kt=0; kt<6; kt++) {
    if (l15 < NH) {
      const float* p = ub + l15*HDIM + w*192 + kt*32 + lg*8;
      float4 x0 = *(const float4*)p;
      float4 x1 = *(const float4*)(p+4);
      short8 s;
      s[0]=(short)f2bf(x0.x); s[1]=(short)f2bf(x0.y); s[2]=(short)f2bf(x0.z); s[3]=(short)f2bf(x0.w);
      s[4]=(short)f2bf(x1.x); s[5]=(short)f2bf(x1.y); s[6]=(short)f2bf(x1.z); s[7]=(short)f2bf(x1.w);
      uf[kt] = s;
    } else {
      short8 s = {0,0,0,0,0,0,0,0};
      uf[kt] = s;
    }
  }
  float cah=0.f, cbh=0.f, cch=0.f;
  if (w==0 && l15<NH) {
    cah = ca[bb*NH + l15]; cbh = cb[bb*NH + l15]; cch = cc[bb*NH + l15];
  }

  float m[NH][3];
  #pragma unroll
  for (int h=0; h<NH; h++) { m[h][0]=0.f; m[h][1]=0.f; m[h][2]=0.f; }
  float rsum=0.f, sasum=0.f, sbsum=0.f;          // live in t<12

  const float* hrow = hs + (long)b*SEQ*HDIM;
  const int srow = t >> 4;         // staging row 0..15
  const int scb  = (t & 15) * 8;   // staging col base (8 f32 per e-step)
  const int swz  = (srow & 7) << 3;

  float4 g[6][2];
  const float4 z4 = make_float4(0.f,0.f,0.f,0.f);
  // stage chunk 0
  #pragma unroll
  for (int e=0; e<6; e++) {
    if (srow < SEQ) {
      const float* p = hrow + (long)srow*HDIM + scb + e*128;
      g[e][0] = *(const float4*)p; g[e][1] = *(const float4*)(p+4);
    } else { g[e][0]=z4; g[e][1]=z4; }
  }
  #pragma unroll
  for (int e=0; e<6; e++)
    *(uint4*)&xbf[srow*HDIM + ((scb + e*128) ^ swz)] = pack8(g[e][0], g[e][1]);
  __syncthreads();

  for (int c=0; c<17; c++) {
    const int s0 = c*16;
    // issue next-chunk global loads early (hide HBM under compute)
    if (c+1 < 17) {
      int sg = (c+1)*16 + srow;
      #pragma unroll
      for (int e=0; e<6; e++) {
        if (sg < SEQ) {
          const float* p = hrow + (long)sg*HDIM + scb + e*128;
          g[e][0] = *(const float4*)p; g[e][1] = *(const float4*)(p+4);
        } else { g[e][0]=z4; g[e][1]=z4; }
      }
    }
    // G1: MFMA over this wave's K-slice
    f32x4 acc = {0.f,0.f,0.f,0.f};
    {
      const int rsw = (l15 & 7) << 3;
      #pragma unroll
      for (int kt=0; kt<6; kt++) {
        int colu = (w*6 + kt)*32 + lg*8;
        uint4 raw = *(const uint4*)&xbf[l15*HDIM + (colu ^ rsw)];
        union { uint4 u4; short8 s8; } cvt; cvt.u4 = raw;
        acc = __builtin_amdgcn_mfma_f32_16x16x32_bf16(cvt.s8, uf[kt], acc, 0, 0, 0);
      }
    }
    if (w > 0) {
      #pragma unroll
      for (int r=0; r<4; r++)
        sred[(w-1)*272 + (lg*4+r)*17 + l15] = acc[r];
    }
    __syncthreads();
    if (w == 0) {
      #pragma unroll
      for (int r=0; r<4; r++) {
        int sr = lg*4 + r;
        float S = acc[r] + sred[0*272 + sr*17 + l15]
                         + sred[1*272 + sr*17 + l15]
                         + sred[2*272 + sr*17 + l15];
        int sg = s0 + sr;
        float sc = S + fmaf(cah, al_s[sg], fmaf(cbh, be_s[sg], cch)) + pbT[sg*16 + l15];
        wl[sr*16 + l15] = (sg < SEQ) ? __expf(sc) : 0.f;
      }
    }
    __syncthreads();
    // Phase C: m_raw += w * x  (x = raw hs, bf16)
    #pragma unroll 4
    for (int cs=0; cs<16; cs++) {
      const int rs = (cs & 7) << 3;
      float x0 = bf2f(xbf[cs*HDIM + ( t        ^ rs)]);
      float x1 = bf2f(xbf[cs*HDIM + ((t + 256) ^ rs)]);
      float x2 = bf2f(xbf[cs*HDIM + ((t + 512) ^ rs)]);
      const float4 wa = *(const float4*)&wl[cs*16 + 0];
      const float4 wb = *(const float4*)&wl[cs*16 + 4];
      const float4 wc = *(const float4*)&wl[cs*16 + 8];
      const float wk[NH] = {wa.x,wa.y,wa.z,wa.w, wb.x,wb.y,wb.z,wb.w, wc.x,wc.y,wc.z,wc.w};
      #pragma unroll
      for (int h=0; h<NH; h++) {
        m[h][0] = fmaf(wk[h], x0, m[h][0]);
        m[h][1] = fmaf(wk[h], x1, m[h][1]);
        m[h][2] = fmaf(wk[h], x2, m[h][2]);
      }
      if (t < NH) {
        float wv = wl[cs*16 + t];
        rsum  += wv;
        sasum  = fmaf(wv, al_s[s0+cs], sasum);
        sbsum  = fmaf(wv, be_s[s0+cs], sbsum);
      }
    }
    __syncthreads();
    if (c+1 < 17) {
      #pragma unroll
      for (int e=0; e<6; e++)
        *(uint4*)&xbf[srow*HDIM + ((scb + e*128) ^ swz)] = pack8(g[e][0], g[e][1]);
    }
    __syncthreads();
  }

  if (t < NH) { hsum[0][t]=rsum; hsum[1][t]=sasum; hsum[2][t]=sbsum; }
  __syncthreads();
  float avv[3], bvv[3], cvv[3];
  #pragma unroll
  for (int k=0;k<3;k++) { avv[k]=Av[t+256*k]; bvv[k]=Bv[t+256*k]; cvv[k]=Cv[t+256*k]; }
  float* mo = mout + (long)bb*(NH*HDIM);
  #pragma unroll
  for (int h=0; h<NH; h++) {
    float invr = 1.0f / hsum[0][h];
    float fa = hsum[1][h]*invr, fb = hsum[2][h]*invr;
    #pragma unroll
    for (int k=0;k<3;k++)
      mo[h*HDIM + t + 256*k] = fmaf(m[h][k], invr, fmaf(fa, avv[k], fmaf(fb, bvv[k], cvv[k])));
  }
}

extern "C" void kernel_launch(void* const* d_in, const int* in_sizes, int n_in,
                              void* d_out, int out_size, void* d_ws, size_t ws_size,
                              hipStream_t stream) {
  (void)in_sizes; (void)n_in; (void)out_size;
  const float* hs   = (const float*)d_in[0];
  const float* Wq   = (const float*)d_in[1];
  const float* bq   = (const float*)d_in[2];
  const float* Wk   = (const float*)d_in[3];
  const float* bk   = (const float*)d_in[4];
  const float* Wv   = (const float*)d_in[5];
  const float* bv   = (const float*)d_in[6];
  const float* Wo   = (const float*)d_in[7];
  const float* bo   = (const float*)d_in[8];
  const float* pe_w = (const float*)d_in[9];
  const float* pe_b = (const float*)d_in[10];
  const float* ln_g = (const float*)d_in[11];
  const float* ln_b = (const float*)d_in[12];
  const float* pos_bias = (const float*)d_in[13];
  float* out = (float*)d_out;

  float* wsf   = (float*)d_ws;
  float* pemid = wsf;               // 768
  float* alpha = pemid + 768;       // 272
  float* beta  = alpha + 272;       // 272
  float* Avec  = beta  + 272;       // 768
  float* Bvec  = Avec  + 768;       // 768
  float* Cvec  = Bvec  + 768;       // 768
  float* pbT   = Cvec  + 768;       // 272*16 = 4352
  float* base  = pbT   + 4352;      // total fixed = 7968 floats

  const long perB = 768L + 36L + 9216L + 9216L + 768L;   // q + (ca,cb,cc) + u + m + ctx
  long availF = (long)(ws_size/4) - 7968;
  long chunkB = (availF > 0) ? (availF / perB) : 0;
  if (chunkB > BTOT) chunkB = BTOT;
  chunkB &= ~63L;
  if (chunkB < 64) chunkB = 64;

  float* qb   = base;
  float* cab  = qb  + chunkB*HDIM;
  float* cbb  = cab + chunkB*NH;
  float* ccb  = cbb + chunkB*NH;
  float* ub   = ccb + chunkB*NH;
  float* mb   = ub  + chunkB*(long)NH*HDIM;
  float* ctxb = mb  + chunkB*(long)NH*HDIM;

  k0_pre<<<dim3(1), dim3(256), 0, stream>>>(pe_w, pe_b, ln_g, ln_b, pos_bias,
                                            pemid, alpha, beta, Avec, Bvec, Cvec, pbT);

  for (long b0 = 0; b0 < BTOT; b0 += chunkB) {
    long cbN = (BTOT - b0 < chunkB) ? (BTOT - b0) : chunkB;
    int mt = (int)(cbN/64);
    // K1: q' = 0.125*((hs[:,mid,:] + pe_mid) @ Wq^T + bq)
    gemm64<<<dim3(mt,12,1), dim3(256), 0, stream>>>(
        hs + b0*(long)SEQ*HDIM + (long)MIDP*HDIM, (long)SEQ*HDIM, 0L,
        Wq, (long)HDIM, 0L, 1,
        qb, (long)HDIM, 0L,
        HDIM, bq, 0L, pemid, 0.125f);
    // K2: u'[b,h,:] = q'[b,h,:] @ Wk_h
    gemm64<<<dim3(mt,12,12), dim3(256), 0, stream>>>(
        qb, (long)HDIM, (long)HD,
        Wk, (long)HDIM, (long)HD*HDIM, 0,
        ub, (long)NH*HDIM, (long)HDIM,
        HD, (const float*)nullptr, 0L, (const float*)nullptr, 1.0f);
    // kp: per-(b,h) pe/bias dot scalars
    int nw = (int)(cbN*NH);
    kp<<<dim3((nw+3)/4), dim3(256), 0, stream>>>(qb, ub, bk, Avec, Bvec, Cvec,
                                                 cab, cbb, ccb, (int)cbN);
    // K3: fused MFMA scores + softmax-weighted mean
    k3_mfma<<<dim3((int)cbN), dim3(256), 0, stream>>>(
        hs, (int)b0, ub, cab, cbb, ccb, alpha, beta, Avec, Bvec, Cvec, pbT, mb);
    // K4: ctx = Wv_h @ m + bv
    gemm64<<<dim3(mt,1,12), dim3(256), 0, stream>>>(
        mb, (long)NH*HDIM, (long)HDIM,
        Wv, (long)HDIM, (long)HD*HDIM, 1,
        ctxb, (long)HDIM, (long)HD,
        HDIM, bv, (long)HD, (const float*)nullptr, 1.0f);
    // K5: out = ctx @ Wo^T + bo
    gemm64<<<dim3(mt,12,1), dim3(256), 0, stream>>>(
        ctxb, (long)HDIM, 0L,
        Wo, (long)HDIM, 0L, 1,
        out + b0*(long)HDIM, (long)HDIM, 0L,
        HDIM, bo, 0L, (const float*)nullptr, 1.0f);
  }
}

// Round 4
// 818.851 us; speedup vs baseline: 2.1158x; 1.0150x over previous
//
#include <hip/hip_runtime.h>
#include <math.h>

#define NH   12
#define HD   64
#define HDIM 768
#define SEQ  257
#define MIDP 128
#define BTOT 2048

typedef __attribute__((ext_vector_type(8))) short short8;
typedef __attribute__((ext_vector_type(4))) float f32x4;

__device__ inline unsigned short f2bf(float x){
  union { float f; unsigned u; } v; v.f = x;
  unsigned r = v.u + 0x7FFFu + ((v.u >> 16) & 1u);
  return (unsigned short)(r >> 16);
}
__device__ inline float bf2f(unsigned short h){
  union { unsigned u; float f; } v; v.u = ((unsigned)h) << 16; return v.f;
}
__device__ inline uint4 pack8(float4 a, float4 b){
  uint4 r;
  r.x = (unsigned)f2bf(a.x) | ((unsigned)f2bf(a.y) << 16);
  r.y = (unsigned)f2bf(a.z) | ((unsigned)f2bf(a.w) << 16);
  r.z = (unsigned)f2bf(b.x) | ((unsigned)f2bf(b.y) << 16);
  r.w = (unsigned)f2bf(b.z) | ((unsigned)f2bf(b.w) << 16);
  return r;
}
__device__ inline float dot4(float4 a, float4 b){
  return fmaf(a.x,b.x, fmaf(a.y,b.y, fmaf(a.z,b.z, a.w*b.w)));
}

// ---------------- K0: moments + pe rank-3 decomposition tables ----------------
// pe[s,j] = alpha_s*A_j + beta_s*B_j + C_j ; alpha=pos*rstd, beta=rstd
__global__ __launch_bounds__(256) void k0_pre(
    const float* __restrict__ pe_w, const float* __restrict__ pe_b,
    const float* __restrict__ ln_g, const float* __restrict__ ln_b,
    const float* __restrict__ pos_bias,
    float* __restrict__ pemid, float* __restrict__ alpha, float* __restrict__ beta,
    float* __restrict__ Av, float* __restrict__ Bv, float* __restrict__ Cv,
    float* __restrict__ pbT) {
  __shared__ float red[5][256];
  const int t = threadIdx.x;
  float sw=0.f, sb=0.f, sww=0.f, swb=0.f, sbb=0.f;
  for (int j=t; j<HDIM; j+=256) {
    float w=pe_w[j], b=pe_b[j];
    sw+=w; sb+=b; sww+=w*w; swb+=w*b; sbb+=b*b;
  }
  red[0][t]=sw; red[1][t]=sb; red[2][t]=sww; red[3][t]=swb; red[4][t]=sbb;
  __syncthreads();
  for (int off=128; off>0; off>>=1) {
    if (t<off) {
      red[0][t]+=red[0][t+off]; red[1][t]+=red[1][t+off]; red[2][t]+=red[2][t+off];
      red[3][t]+=red[3][t+off]; red[4][t]+=red[4][t+off];
    }
    __syncthreads();
  }
  const float inv = 1.0f/(float)HDIM;
  const float mw=red[0][0]*inv, mc=red[1][0]*inv;
  const float Vw =red[2][0]*inv - mw*mw;
  const float Cwc=red[3][0]*inv - mw*mc;
  const float Vc =red[4][0]*inv - mc*mc;
  for (int s=t; s<272; s+=256) {
    if (s < SEQ) {
      float pos = (float)(s - MIDP) / ((float)MIDP + 1e-6f);
      float var = pos*pos*Vw + 2.f*pos*Cwc + Vc;
      float rstd = rsqrtf(var + 1e-5f);
      alpha[s] = pos*rstd; beta[s] = rstd;
    } else { alpha[s] = 0.f; beta[s] = 0.f; }
  }
  const float rstd0 = rsqrtf(Vc + 1e-5f);
  for (int j=t; j<HDIM; j+=256) {
    float g = ln_g[j];
    Av[j] = (pe_w[j]-mw)*g;
    Bv[j] = (pe_b[j]-mc)*g;
    Cv[j] = ln_b[j];
    pemid[j] = (pe_b[j]-mc)*rstd0*g + ln_b[j];
  }
  for (int i=t; i<272*16; i+=256) {
    int s = i>>4, h = i&15;
    pbT[i] = (s<SEQ && h<NH) ? pos_bias[h*SEQ+s] : 0.f;
  }
}

// ---------------- tiled fp32 GEMM with epilogue scale ----------------
__global__ __launch_bounds__(256) void gemm64(
    const float* __restrict__ A, long lda, long aoffz,
    const float* __restrict__ Bm, long ldb, long boffz, int bT,
    float* __restrict__ C, long ldc, long coffz,
    int K,
    const float* __restrict__ bias, long biasoffz,
    const float* __restrict__ avec, float scale) {
  __shared__ __align__(16) float As[16][68];
  __shared__ __align__(16) float Bs[16][68];
  const int tid = threadIdx.x;
  const int tx = tid & 15, ty = tid >> 4;
  const int z = blockIdx.z;
  const long n0 = (long)blockIdx.y * 64;
  A  += (long)blockIdx.x*64*lda + (long)z*aoffz;
  Bm += (long)z*boffz;
  C  += (long)blockIdx.x*64*ldc + n0 + (long)z*coffz;
  float acc[4][4] = {};
  const int lm = tid & 63;
  const int lk = tid >> 6;

  for (int k0 = 0; k0 < K; k0 += 16) {
    float4 a = *(const float4*)&A[(long)lm*lda + k0 + lk*4];
    if (avec) {
      float4 av = *(const float4*)&avec[k0 + lk*4];
      a.x += av.x; a.y += av.y; a.z += av.z; a.w += av.w;
    }
    As[lk*4+0][lm]=a.x; As[lk*4+1][lm]=a.y; As[lk*4+2][lm]=a.z; As[lk*4+3][lm]=a.w;
    if (bT) {
      float4 b = *(const float4*)&Bm[(n0+lm)*ldb + k0 + lk*4];
      Bs[lk*4+0][lm]=b.x; Bs[lk*4+1][lm]=b.y; Bs[lk*4+2][lm]=b.z; Bs[lk*4+3][lm]=b.w;
    } else {
      #pragma unroll
      for (int i=0;i<4;i++)
        Bs[lk*4+i][lm] = Bm[(long)(k0+lk*4+i)*ldb + n0 + lm];
    }
    __syncthreads();
    #pragma unroll
    for (int k=0;k<16;k++) {
      float4 a4 = *(const float4*)&As[k][ty*4];
      float4 b4 = *(const float4*)&Bs[k][tx*4];
      float aa[4] = {a4.x,a4.y,a4.z,a4.w};
      float bb[4] = {b4.x,b4.y,b4.z,b4.w};
      #pragma unroll
      for (int i=0;i<4;i++)
        #pragma unroll
        for (int j=0;j<4;j++)
          acc[i][j] = fmaf(aa[i], bb[j], acc[i][j]);
    }
    __syncthreads();
  }
  float4 bs = make_float4(0.f,0.f,0.f,0.f);
  if (bias) bs = *(const float4*)&bias[(long)z*biasoffz + n0 + tx*4];
  #pragma unroll
  for (int i=0;i<4;i++) {
    float4 o;
    o.x = (acc[i][0]+bs.x)*scale; o.y = (acc[i][1]+bs.y)*scale;
    o.z = (acc[i][2]+bs.z)*scale; o.w = (acc[i][3]+bs.w)*scale;
    *(float4*)&C[(long)(ty*4+i)*ldc + tx*4] = o;
  }
}

// ---------------- kp: per-(b,h) scalars ca=u'.A, cb=u'.B, cc=u'.C + q'.bk ----------------
__global__ __launch_bounds__(256) void kp(
    const float* __restrict__ q, const float* __restrict__ u, const float* __restrict__ bk,
    const float* __restrict__ Av, const float* __restrict__ Bv, const float* __restrict__ Cv,
    float* __restrict__ ca, float* __restrict__ cb, float* __restrict__ cc, int nb) {
  const int wid = blockIdx.x*4 + (threadIdx.x >> 6);
  const int lane = threadIdx.x & 63;
  if (wid >= nb*NH) return;
  const int b = wid / NH, h = wid % NH;
  const float* up = u + (long)b*(NH*HDIM) + h*HDIM;
  float pa=0.f, pb_=0.f, pc=0.f;
  #pragma unroll
  for (int e=0;e<3;e++) {
    int c4 = (lane + 64*e)*4;
    float4 uu = *(const float4*)&up[c4];
    pa += dot4(uu, *(const float4*)&Av[c4]);
    pb_+= dot4(uu, *(const float4*)&Bv[c4]);
    pc += dot4(uu, *(const float4*)&Cv[c4]);
  }
  if (lane < 16) {
    float4 qq = *(const float4*)&q[(long)b*HDIM + h*HD + lane*4];
    float4 bb = *(const float4*)&bk[h*HD + lane*4];
    pc += dot4(qq, bb);
  }
  #pragma unroll
  for (int mlog=0; mlog<6; mlog++) {
    int msk = 1<<mlog;
    pa += __shfl_xor(pa, msk);
    pb_+= __shfl_xor(pb_, msk);
    pc += __shfl_xor(pc, msk);
  }
  if (lane == 0) { ca[wid]=pa; cb[wid]=pb_; cc[wid]=pc; }
}

// ---------------- K3 v3: all-MFMA scores + distributed exp + MFMA PV ----------------
// Block per batch, 16-row chunks of raw hs as swizzled bf16 in LDS.
// Score: S(16s x 16h) = x*u'^T, K=768 split over 4 waves, cross-wave reduce in sred.
// Exp: distributed — lane (wave w, lg, l15) handles (row = w*4+lg, head = l15).
// PV:  m(16h x 768j) += w^T * x via 12 mfma/wave (K=16 in low half of K=32).
__global__ __launch_bounds__(256, 3) void k3_mfma(
    const float* __restrict__ hs, int b0,
    const float* __restrict__ u,
    const float* __restrict__ ca, const float* __restrict__ cb, const float* __restrict__ cc,
    const float* __restrict__ alpha, const float* __restrict__ beta,
    const float* __restrict__ Av, const float* __restrict__ Bv, const float* __restrict__ Cv,
    const float* __restrict__ pbT, float* __restrict__ mout) {
  const int t   = threadIdx.x;
  const int l   = t & 63;
  const int w   = t >> 6;
  const int l15 = l & 15;
  const int lg  = l >> 4;
  const int bb  = blockIdx.x;
  const int b   = b0 + bb;

  __shared__ __align__(16) unsigned short xbf[16*768];   // 24576 B
  __shared__ float sred[4][16][17];                      //  4352 B
  __shared__ __align__(16) unsigned short wl[16][16];    //   512 B  [h][s]
  __shared__ float al_s[272], be_s[272];                 //  2176 B
  __shared__ float hsum[3][4][16];                       //   768 B

  for (int i=t; i<272; i+=256) { al_s[i]=alpha[i]; be_s[i]=beta[i]; }

  // u'-fragments (B operand of score MFMA), wave w covers K-cols [w*192, w*192+192)
  const float* ub = u + (long)bb*(NH*HDIM);
  short8 uf[6];
  #pragma unroll
  for (int kt=0; kt<6; kt++) {
    if (l15 < NH) {
      const float* p = ub + l15*HDIM + w*192 + kt*32 + lg*8;
      float4 x0 = *(const float4*)p;
      float4 x1 = *(const float4*)(p+4);
      short8 s;
      s[0]=(short)f2bf(x0.x); s[1]=(short)f2bf(x0.y); s[2]=(short)f2bf(x0.z); s[3]=(short)f2bf(x0.w);
      s[4]=(short)f2bf(x1.x); s[5]=(short)f2bf(x1.y); s[6]=(short)f2bf(x1.z); s[7]=(short)f2bf(x1.w);
      uf[kt] = s;
    } else {
      short8 s = {0,0,0,0,0,0,0,0};
      uf[kt] = s;
    }
  }
  float cah=0.f, cbh=0.f, cch=0.f;
  if (l15 < NH) {
    cah = ca[bb*NH + l15]; cbh = cb[bb*NH + l15]; cch = cc[bb*NH + l15];
  }

  f32x4 pv[12];
  #pragma unroll
  for (int i=0;i<12;i++) { f32x4 zz = {0.f,0.f,0.f,0.f}; pv[i] = zz; }
  float rs_p=0.f, sa_p=0.f, sb_p=0.f;

  const float* hrow = hs + (long)b*SEQ*HDIM;
  const int srow = t >> 4;         // staging row 0..15
  const int scb  = (t & 15) * 8;   // staging col base (8 f32 per e-step)
  const int swz  = (srow & 7) << 3;

  float4 g[6][2];
  const float4 z4 = make_float4(0.f,0.f,0.f,0.f);
  // stage chunk 0
  #pragma unroll
  for (int e=0; e<6; e++) {
    const float* p = hrow + (long)srow*HDIM + scb + e*128;
    g[e][0] = *(const float4*)p; g[e][1] = *(const float4*)(p+4);
  }
  #pragma unroll
  for (int e=0; e<6; e++)
    *(uint4*)&xbf[srow*HDIM + ((scb + e*128) ^ swz)] = pack8(g[e][0], g[e][1]);
  __syncthreads();

  for (int c=0; c<17; c++) {
    // issue next-chunk global loads early
    if (c+1 < 17) {
      int sg = (c+1)*16 + srow;
      #pragma unroll
      for (int e=0; e<6; e++) {
        if (sg < SEQ) {
          const float* p = hrow + (long)sg*HDIM + scb + e*128;
          g[e][0] = *(const float4*)p; g[e][1] = *(const float4*)(p+4);
        } else { g[e][0]=z4; g[e][1]=z4; }
      }
    }
    // ---- score MFMA over this wave's K-slice ----
    f32x4 acc = {0.f,0.f,0.f,0.f};
    {
      const int rsw = (l15 & 7) << 3;
      #pragma unroll
      for (int kt=0; kt<6; kt++) {
        int colu = (w*6 + kt)*32 + lg*8;
        uint4 raw = *(const uint4*)&xbf[l15*HDIM + (colu ^ rsw)];
        union { uint4 u4; short8 s8; } cvt; cvt.u4 = raw;
        acc = __builtin_amdgcn_mfma_f32_16x16x32_bf16(cvt.s8, uf[kt], acc, 0, 0, 0);
      }
    }
    #pragma unroll
    for (int r=0; r<4; r++)
      sred[w][lg*4+r][l15] = acc[r];
    __syncthreads();                       // BAR1: sred ready
    // ---- distributed exp: one (row, head) per lane ----
    {
      const int srw = w*4 + lg;
      const int sg  = c*16 + srw;
      float S = sred[0][srw][l15] + sred[1][srw][l15]
              + sred[2][srw][l15] + sred[3][srw][l15];
      float sc = S + fmaf(cah, al_s[sg], fmaf(cbh, be_s[sg], cch)) + pbT[sg*16 + l15];
      float wv = (sg < SEQ && l15 < NH) ? __expf(sc) : 0.f;
      unsigned short wb16 = f2bf(wv);
      float wvr = bf2f(wb16);
      rs_p += wvr;
      sa_p  = fmaf(wvr, al_s[sg], sa_p);
      sb_p  = fmaf(wvr, be_s[sg], sb_p);
      wl[l15][srw] = wb16;
    }
    __syncthreads();                       // BAR2: wl ready
    // ---- PV MFMA: m[h][j] += sum_s w[s,h]*x[s,j] ----
    {
      short8 af;
      if (lg < 2) af = *(const short8*)&wl[l15][lg*8];
      else { short8 zz = {0,0,0,0,0,0,0,0}; af = zz; }
      #pragma unroll
      for (int tau=0; tau<12; tau++) {
        short8 bfr = {0,0,0,0,0,0,0,0};
        if (lg < 2) {
          const int j = w*192 + tau*16 + l15;
          #pragma unroll
          for (int e=0; e<8; e++) {
            const int s = lg*8 + e;
            bfr[e] = (short)xbf[s*HDIM + (j ^ ((s&7)<<3))];
          }
        }
        pv[tau] = __builtin_amdgcn_mfma_f32_16x16x32_bf16(af, bfr, pv[tau], 0, 0, 0);
      }
    }
    __syncthreads();                       // BAR3: xbf free
    if (c+1 < 17) {
      #pragma unroll
      for (int e=0; e<6; e++)
        *(uint4*)&xbf[srow*HDIM + ((scb + e*128) ^ swz)] = pack8(g[e][0], g[e][1]);
    }
    __syncthreads();                       // BAR4: xbf(c+1) ready
  }

  // reduce per-lane softmax partials over the 4 lane-groups (rows)
  rs_p += __shfl_xor(rs_p, 16); rs_p += __shfl_xor(rs_p, 32);
  sa_p += __shfl_xor(sa_p, 16); sa_p += __shfl_xor(sa_p, 32);
  sb_p += __shfl_xor(sb_p, 16); sb_p += __shfl_xor(sb_p, 32);
  if (l < 16) { hsum[0][w][l15]=rs_p; hsum[1][w][l15]=sa_p; hsum[2][w][l15]=sb_p; }
  __syncthreads();

  float* mo = mout + (long)bb*(NH*HDIM);
  #pragma unroll
  for (int r=0; r<4; r++) {
    const int h = lg*4 + r;
    if (h < NH) {
      float rsum = hsum[0][0][h]+hsum[0][1][h]+hsum[0][2][h]+hsum[0][3][h];
      float sas  = hsum[1][0][h]+hsum[1][1][h]+hsum[1][2][h]+hsum[1][3][h];
      float sbs  = hsum[2][0][h]+hsum[2][1][h]+hsum[2][2][h]+hsum[2][3][h];
      float invr = 1.0f/rsum;
      float fa = sas*invr, fb = sbs*invr;
      #pragma unroll
      for (int tau=0; tau<12; tau++) {
        const int j = w*192 + tau*16 + l15;
        mo[h*HDIM + j] = fmaf(pv[tau][r], invr, fmaf(fa, Av[j], fmaf(fb, Bv[j], Cv[j])));
      }
    }
  }
}

extern "C" void kernel_launch(void* const* d_in, const int* in_sizes, int n_in,
                              void* d_out, int out_size, void* d_ws, size_t ws_size,
                              hipStream_t stream) {
  (void)in_sizes; (void)n_in; (void)out_size;
  const float* hs   = (const float*)d_in[0];
  const float* Wq   = (const float*)d_in[1];
  const float* bq   = (const float*)d_in[2];
  const float* Wk   = (const float*)d_in[3];
  const float* bk   = (const float*)d_in[4];
  const float* Wv   = (const float*)d_in[5];
  const float* bv   = (const float*)d_in[6];
  const float* Wo   = (const float*)d_in[7];
  const float* bo   = (const float*)d_in[8];
  const float* pe_w = (const float*)d_in[9];
  const float* pe_b = (const float*)d_in[10];
  const float* ln_g = (const float*)d_in[11];
  const float* ln_b = (const float*)d_in[12];
  const float* pos_bias = (const float*)d_in[13];
  float* out = (float*)d_out;

  float* wsf   = (float*)d_ws;
  float* pemid = wsf;               // 768
  float* alpha = pemid + 768;       // 272
  float* beta  = alpha + 272;       // 272
  float* Avec  = beta  + 272;       // 768
  float* Bvec  = Avec  + 768;       // 768
  float* Cvec  = Bvec  + 768;       // 768
  float* pbT   = Cvec  + 768;       // 272*16 = 4352
  float* base  = pbT   + 4352;      // total fixed = 7968 floats

  const long perB = 768L + 36L + 9216L + 9216L + 768L;   // q + (ca,cb,cc) + u + m + ctx
  long availF = (long)(ws_size/4) - 7968;
  long chunkB = (availF > 0) ? (availF / perB) : 0;
  if (chunkB > BTOT) chunkB = BTOT;
  chunkB &= ~63L;
  if (chunkB < 64) chunkB = 64;

  float* qb   = base;
  float* cab  = qb  + chunkB*HDIM;
  float* cbb  = cab + chunkB*NH;
  float* ccb  = cbb + chunkB*NH;
  float* ub   = ccb + chunkB*NH;
  float* mb   = ub  + chunkB*(long)NH*HDIM;
  float* ctxb = mb  + chunkB*(long)NH*HDIM;

  k0_pre<<<dim3(1), dim3(256), 0, stream>>>(pe_w, pe_b, ln_g, ln_b, pos_bias,
                                            pemid, alpha, beta, Avec, Bvec, Cvec, pbT);

  for (long b0 = 0; b0 < BTOT; b0 += chunkB) {
    long cbN = (BTOT - b0 < chunkB) ? (BTOT - b0) : chunkB;
    int mt = (int)(cbN/64);
    // K1: q' = 0.125*((hs[:,mid,:] + pe_mid) @ Wq^T + bq)
    gemm64<<<dim3(mt,12,1), dim3(256), 0, stream>>>(
        hs + b0*(long)SEQ*HDIM + (long)MIDP*HDIM, (long)SEQ*HDIM, 0L,
        Wq, (long)HDIM, 0L, 1,
        qb, (long)HDIM, 0L,
        HDIM, bq, 0L, pemid, 0.125f);
    // K2: u'[b,h,:] = q'[b,h,:] @ Wk_h
    gemm64<<<dim3(mt,12,12), dim3(256), 0, stream>>>(
        qb, (long)HDIM, (long)HD,
        Wk, (long)HDIM, (long)HD*HDIM, 0,
        ub, (long)NH*HDIM, (long)HDIM,
        HD, (const float*)nullptr, 0L, (const float*)nullptr, 1.0f);
    // kp: per-(b,h) pe/bias dot scalars
    int nw = (int)(cbN*NH);
    kp<<<dim3((nw+3)/4), dim3(256), 0, stream>>>(qb, ub, bk, Avec, Bvec, Cvec,
                                                 cab, cbb, ccb, (int)cbN);
    // K3: fused MFMA scores + softmax-weighted mean
    k3_mfma<<<dim3((int)cbN), dim3(256), 0, stream>>>(
        hs, (int)b0, ub, cab, cbb, ccb, alpha, beta, Avec, Bvec, Cvec, pbT, mb);
    // K4: ctx = Wv_h @ m + bv
    gemm64<<<dim3(mt,1,12), dim3(256), 0, stream>>>(
        mb, (long)NH*HDIM, (long)HDIM,
        Wv, (long)HDIM, (long)HD*HDIM, 1,
        ctxb, (long)HDIM, (long)HD,
        HDIM, bv, (long)HD, (const float*)nullptr, 1.0f);
    // K5: out = ctx @ Wo^T + bo
    gemm64<<<dim3(mt,12,1), dim3(256), 0, stream>>>(
        ctxb, (long)HDIM, 0L,
        Wo, (long)HDIM, 0L, 1,
        out + b0*(long)HDIM, (long)HDIM, 0L,
        HDIM, bo, 0L, (const float*)nullptr, 1.0f);
  }
}